// Round 3
// baseline (258.347 us; speedup 1.0000x reference)
//
#include <hip/hip_runtime.h>
#include <math.h>

// Problem constants
#define BATCH   64
#define SAMP    32
#define SIGLEN  19530           // sum_{k=1..6} 5^k
#define NROWS   (BATCH * SAMP)  // 2048
#define NF2     (SIGLEN / 2)    // 9765 float2 per row
#define NF4     4882            // threads 0..4881 handle 2 float2; thread 4882 handles 1
#define NBISECT 40              // fp32 bisection on [0,2] fixed-point after ~30 iters

// Level boundaries (element index): level k occupies [LB[k-1], LB[k])
// LB = {0, 5, 30, 155, 780, 3905, 19530}

__device__ __forceinline__ int level0(int l) {
    return (l >= 5) + (l >= 30) + (l >= 155) + (l >= 780) + (l >= 3905);
}

// Alignment-aware sum of squares over row[lo,hi).
// par = 2*(bs&1): element index e has 16B-aligned address iff e % 4 == par
// (row base byte = bs*78120, 78120 % 16 == 8).
__device__ __forceinline__ float sumsq_region(const float* __restrict__ row,
                                              int lo, int hi, int par, int t) {
    float acc = 0.f;
    int vstart = lo + ((par - lo) % 4 + 4) % 4;
    if (vstart > hi) vstart = hi;
    const int nvec = (hi - vstart) >> 2;
    // head (<=3 elems)
    for (int l = lo + t; l < vstart; l += 256) { float v = row[l]; acc += v * v; }
    // aligned float4 body
    const float4* __restrict__ p = (const float4*)(row + vstart);
    for (int j = t; j < nvec; j += 256) {
        float4 v = p[j];
        acc += v.x * v.x + v.y * v.y + v.z * v.z + v.w * v.w;
    }
    // tail (<=3 elems)
    for (int l = vstart + 4 * nvec + t; l < hi; l += 256) { float v = row[l]; acc += v * v; }
    return acc;
}

// ---------------------------------------------------------------------------
// Kernel A: per-(b,s) row -> 6 per-level sums of x^2 -> bisection root ->
// w[m] = root^(m+1)/SAMP (6 floats/row). One 256-thread block per row.
// ---------------------------------------------------------------------------
__global__ __launch_bounds__(256) void sums_bisect_kernel(
        const float* __restrict__ x, float* __restrict__ pw) {
    const int bs = blockIdx.x;               // 0..2047
    const float* __restrict__ row = x + (size_t)bs * SIGLEN;
    const int t = threadIdx.x;
    const int par = (bs & 1) * 2;

    float a1 = sumsq_region(row,    0,     5, par, t);
    float a2 = sumsq_region(row,    5,    30, par, t);
    float a3 = sumsq_region(row,   30,   155, par, t);
    float a4 = sumsq_region(row,  155,   780, par, t);
    float a5 = sumsq_region(row,  780,  3905, par, t);
    float a6 = sumsq_region(row, 3905, SIGLEN, par, t);

    // Wave (64-lane) butterfly reduction of the 6 accumulators
    #pragma unroll
    for (int off = 32; off > 0; off >>= 1) {
        a1 += __shfl_xor(a1, off);
        a2 += __shfl_xor(a2, off);
        a3 += __shfl_xor(a3, off);
        a4 += __shfl_xor(a4, off);
        a5 += __shfl_xor(a5, off);
        a6 += __shfl_xor(a6, off);
    }

    __shared__ float red[4][6];
    const int wave = t >> 6, lane = t & 63;
    if (lane == 0) {
        red[wave][0] = a1; red[wave][1] = a2; red[wave][2] = a3;
        red[wave][3] = a4; red[wave][4] = a5; red[wave][5] = a6;
    }
    __syncthreads();

    if (t == 0) {
        float s1 = 0.f, s2 = 0.f, s3 = 0.f, s4 = 0.f, s5 = 0.f, s6 = 0.f;
        #pragma unroll
        for (int w = 0; w < 4; ++w) {
            s1 += red[w][0]; s2 += red[w][1]; s3 += red[w][2];
            s4 += red[w][3]; s5 += red[w][4]; s6 += red[w][5];
        }
        const float total = s1 + s2 + s3 + s4 + s5 + s6;
        const float nq = 1.0f + total;
        // phi(x) with C=4, a=1: x<=4 -> x ; else 8 - 16/x
        const float phi = (nq > 4.0f) ? (8.0f - 16.0f / nq) : nq;
        const float c0 = 1.0f - phi;
        const bool fin = isfinite(c0) && isfinite(total);

        float lo = 0.0f, hi = 2.0f;
        #pragma unroll 4
        for (int i = 0; i < NBISECT; ++i) {
            const float mid = 0.5f * (lo + hi);
            const float u = mid * mid;
            const float p = ((((((s6 * u + s5) * u + s4) * u + s3) * u + s2) * u + s1) * u) + c0;
            const bool neg = p < 0.0f;      // NaN -> false -> hi = mid (matches jnp.where)
            lo = neg ? mid : lo;
            hi = neg ? hi : mid;
        }
        float root = 0.5f * (lo + hi);
        if (!fin) root = 0.0f;
        root = fminf(root, 1.0f);

        float* dst = pw + (size_t)bs * 6;
        const float inv = 1.0f / SAMP;
        float w1 = root;
        float w2 = w1 * root, w3 = w2 * root, w4 = w3 * root, w5 = w4 * root, w6 = w5 * root;
        dst[0] = w1 * inv; dst[1] = w2 * inv; dst[2] = w3 * inv;
        dst[3] = w4 * inv; dst[4] = w5 * inv; dst[5] = w6 * inv;
    }
}

// ---------------------------------------------------------------------------
// Kernel B: out[b,l] = sum_s x[b,s,l] * pw[b,s][level(l)]   (1/32 pre-folded)
// Each thread handles 4 consecutive elements (2 float2). Grid: (20, 64).
// ---------------------------------------------------------------------------
__global__ __launch_bounds__(256) void scale_mean_kernel(
        const float* __restrict__ x, const float* __restrict__ pw,
        float* __restrict__ out) {
    const int b = blockIdx.y;
    const int t = threadIdx.x;

    __shared__ float w[SAMP * 6];   // [s*6 + lev]
    if (t < SAMP * 6) w[t] = pw[(size_t)b * (SAMP * 6) + t];
    __syncthreads();

    const int q = blockIdx.x * 256 + t;      // 4-element group index
    if (q > NF4) return;
    const bool full = (q < NF4);             // thread NF4 handles only 2 elems

    const int e0 = 4 * q;
    const int levA = level0(e0);
    const int levZ = full ? level0(e0 + 3) : level0(e0 + 1);

    const float2* __restrict__ xp =
        (const float2*)x + (size_t)b * (SAMP * NF2) + 2 * q;

    float acc0 = 0.f, acc1 = 0.f, acc2 = 0.f, acc3 = 0.f;
    if (levA == levZ) {
        #pragma unroll 8
        for (int s = 0; s < SAMP; ++s) {
            const float ws = w[s * 6 + levA];          // broadcast LDS read
            const float2 v0 = xp[(size_t)s * NF2];
            acc0 += v0.x * ws; acc1 += v0.y * ws;
            if (full) {
                const float2 v1 = xp[(size_t)s * NF2 + 1];
                acc2 += v1.x * ws; acc3 += v1.y * ws;
            }
        }
    } else {                                           // <=4 straddling threads/row
        const int l0 = level0(e0), l1 = level0(e0 + 1);
        const int l2 = level0(e0 + 2), l3 = level0(e0 + 3);
        #pragma unroll 8
        for (int s = 0; s < SAMP; ++s) {
            const float2 v0 = xp[(size_t)s * NF2];
            acc0 += v0.x * w[s * 6 + l0]; acc1 += v0.y * w[s * 6 + l1];
            if (full) {
                const float2 v1 = xp[(size_t)s * NF2 + 1];
                acc2 += v1.x * w[s * 6 + l2]; acc3 += v1.y * w[s * 6 + l3];
            }
        }
    }

    float2* __restrict__ op = (float2*)out + (size_t)b * NF2 + 2 * q;
    float2 r0; r0.x = acc0; r0.y = acc1;
    op[0] = r0;
    if (full) { float2 r1; r1.x = acc2; r1.y = acc3; op[1] = r1; }
}

extern "C" void kernel_launch(void* const* d_in, const int* in_sizes, int n_in,
                              void* d_out, int out_size, void* d_ws, size_t ws_size,
                              hipStream_t stream) {
    const float* x = (const float*)d_in[0];   // [64,32,19530] fp32
    float* out = (float*)d_out;               // [64,19530] fp32
    float* pw = (float*)d_ws;                 // 2048*6 floats = 48 KiB scratch

    sums_bisect_kernel<<<NROWS, 256, 0, stream>>>(x, pw);

    dim3 gridB((NF4 + 1 + 255) / 256, BATCH); // (20, 64)
    scale_mean_kernel<<<gridB, 256, 0, stream>>>(x, pw, out);
}